// Round 8
// baseline (2351.735 us; speedup 1.0000x reference)
//
#include <hip/hip_runtime.h>
#include <math.h>

#define NXY 513
#define NIN 511
#define NL3 3
#define NE4 4
#define NB 12
#define GLD 512

static constexpr long FS  = (long)NE4 * NL3 * NXY * NXY;   // 3,158,028 floats
static constexpr long GSZ = (long)NB * GLD * GLD;          // 3,145,728 elements
static constexpr int  NSTEPS = 4;

static constexpr double dF0 = 9.375e-05;
static constexpr double dDX = 10000.0;
static constexpr float ZFBCf     = (float)(0.2 / (1.0 + 0.5 * 0.2));
static constexpr float JACCf     = (float)(1.0 / (dF0 * dDX * dDX));
static constexpr float HYPCf     = (float)(2.0e9 / (dF0 * dF0) / (dDX*dDX*dDX*dDX*dDX*dDX));
static constexpr float BFCf      = (float)(2.0 / (2.0 * dF0 * dDX * dDX * (-2900.0)));
static constexpr float INVF0DX2f = (float)(1.0 / ((dF0 * dDX) * (dF0 * dDX)));

typedef short  bf16x8 __attribute__((ext_vector_type(8)));
typedef float  f32x4  __attribute__((ext_vector_type(4)));
typedef unsigned int u32;
typedef __attribute__((address_space(1))) const u32 GAS;
typedef __attribute__((address_space(3))) u32 LAS;
#define GLDS(gp, lp) __builtin_amdgcn_global_load_lds((GAS*)(gp), (LAS*)(lp), 16, 0, 0)

__device__ __forceinline__ unsigned short f2bf(float x) {
    unsigned int u = __float_as_uint(x);
    return (unsigned short)((u + 0x7FFFu + ((u >> 16) & 1u)) >> 16);
}
__device__ __forceinline__ float bf2f(unsigned short h) {
    return __uint_as_float(((unsigned int)h) << 16);
}

// ---------------- DST matrix (bf16 hi/lo) -------------------------------------------------------
__global__ void initS_kernel(unsigned short* __restrict__ Sh, unsigned short* __restrict__ Sl) {
    int k = blockIdx.x * 256 + threadIdx.x;
    int n = blockIdx.y;
    if (k >= GLD || n >= GLD) return;
    float v = 0.f;
    if (n < NIN && k < NIN) {
        int m = ((n + 1) * (k + 1)) & 1023;
        v = (float)(0.0625 * sin(M_PI * (double)m / 512.0));
    }
    unsigned short hs = f2bf(v);
    Sh[n * GLD + k] = hs;
    Sl[n * GLD + k] = f2bf(v - bf2f(hs));
}

// ---------------- fused rhs + l2m: one block = one ensemble tile, 3 layers sequential -----------
__global__ __launch_bounds__(256) void fused_rhs_l2m(
    float* __restrict__ kq, unsigned short* __restrict__ Gh, unsigned short* __restrict__ Gl,
    const float* __restrict__ y, const float* __restrict__ wind, const float* __restrict__ Cl2m)
{
    __shared__ float ps[22][72];
    __shared__ float qs[22][72];
    __shared__ float l1[22][72];
    __shared__ float l2[22][72];
    const int e  = blockIdx.z;
    const int x0 = 1 + blockIdx.y * 16;
    const int y0 = 1 + blockIdx.x * 64;
    const int t  = threadIdx.x;
    const float* q = y;
    const float* p = y + FS;
    float rhs[4][3];

#define LAPBC(a, i, j, gx, gy) \
    ((gy) == 0       ? ZFBCf * (a[i][(j)+1] - a[i][j]) : \
     (gy) == NXY-1   ? ZFBCf * (a[i][(j)-1] - a[i][j]) : \
     (gx) == 0       ? ZFBCf * (a[(i)+1][j] - a[i][j]) : \
     (gx) == NXY-1   ? ZFBCf * (a[(i)-1][j] - a[i][j]) : \
     a[(i)+1][j] + a[(i)-1][j] + a[i][(j)+1] + a[i][(j)-1] - 4.f * a[i][j])

#pragma unroll
    for (int l = 0; l < 3; ++l) {
        __syncthreads();   // protect ps/qs from previous layer's readers
        const int c = e * NL3 + l;
        const size_t off = (size_t)c * NXY * NXY;
        const float* pp = p + off;
        const float* qp = q + off;
        for (int idx = t; idx < 22 * 70; idx += 256) {
            int i = idx / 70, j = idx % 70;
            int gx = x0 - 3 + i, gy = y0 - 3 + j;
            bool in = (gx >= 0 && gx < NXY && gy >= 0 && gy < NXY);
            size_t go = (size_t)gx * NXY + gy;
            ps[i][j] = in ? pp[go] : 0.f;
            qs[i][j] = in ? qp[go] : 0.f;
        }
        __syncthreads();
        for (int idx = t; idx < 20 * 68; idx += 256) {
            int i = 1 + idx / 68, j = 1 + idx % 68;
            int gx = x0 - 3 + i, gy = y0 - 3 + j;
            float v = 0.f;
            if (gx >= 0 && gx < NXY && gy >= 0 && gy < NXY) v = LAPBC(ps, i, j, gx, gy);
            l1[i][j] = v;
        }
        __syncthreads();
        for (int idx = t; idx < 18 * 66; idx += 256) {
            int i = 2 + idx / 66, j = 2 + idx % 66;
            int gx = x0 - 3 + i, gy = y0 - 3 + j;
            float v = 0.f;
            if (gx >= 0 && gx < NXY && gy >= 0 && gy < NXY) v = LAPBC(l1, i, j, gx, gy);
            l2[i][j] = v;
        }
        __syncthreads();
#pragma unroll
        for (int u = 0; u < 4; ++u) {
            int idx = t + 256 * u;
            int i = 3 + idx / 64, j = 3 + idx % 64;
            int gx = x0 - 3 + i, gy = y0 - 3 + j;
            if (gx > NIN || gy > NIN) { rhs[u][l] = 0.f; continue; }
            float fmm=qs[i-1][j-1], fm0=qs[i-1][j], fmp=qs[i-1][j+1];
            float f0m=qs[i][j-1],                    f0p=qs[i][j+1];
            float fpm=qs[i+1][j-1], fp0=qs[i+1][j], fpp=qs[i+1][j+1];
            float gmm=ps[i-1][j-1], gm0=ps[i-1][j], gmp=ps[i-1][j+1];
            float g0m=ps[i][j-1],   g00=ps[i][j],   g0p=ps[i][j+1];
            float gpm=ps[i+1][j-1], gp0=ps[i+1][j], gpp=ps[i+1][j+1];
            float J1 = (fp0 - fm0) * (g0p - g0m) - (gp0 - gm0) * (f0p - f0m);
            float J2 = fp0 * (gpp - gpm) - fm0 * (gmp - gmm);
            float J3 = f0p * (gpp - gmp) - f0m * (gpm - gmm);
            float J4 = g0p * (fpp - fmp) - g0m * (fpm - fmm);
            float J5 = gp0 * (fpp - fpm) - gm0 * (fmp - fmm);
            float jac = (J1 + J2 - J3 + J4 - J5) * (1.0f / 12.0f);
            float lap3 = l2[i+1][j] + l2[i-1][j] + l2[i][j+1] + l2[i][j-1] - 4.f * l2[i][j];
            float v = JACCf * jac - HYPCf * lap3;
            if (l == 0)       v += wind[(size_t)(gx-1) * NIN + (gy-1)];
            if (l == NL3-1)   v += BFCf * (gp0 + gm0 + g0p + g0m - 4.f * g00);
            rhs[u][l] = v;
            kq[off + (size_t)gx * NXY + gy] = v;
        }
    }
#undef LAPBC

    // layer->mode transform + bf16 hi/lo writes (pads zeroed at gx==512 / gy==512)
#pragma unroll
    for (int u = 0; u < 4; ++u) {
        int idx = t + 256 * u;
        int i = 3 + idx / 64, j = 3 + idx % 64;
        int gx = x0 - 3 + i, gy = y0 - 3 + j;
        size_t go = (size_t)(e * NL3) * GLD * GLD + (size_t)(gx-1) * GLD + (gy-1);
        if (gx > NIN || gy > NIN) {
#pragma unroll
            for (int m = 0; m < 3; ++m) {
                Gh[go + (size_t)m*GLD*GLD] = 0; Gl[go + (size_t)m*GLD*GLD] = 0;
            }
            continue;
        }
        float f0 = rhs[u][0], f1 = rhs[u][1], f2 = rhs[u][2];
        float v[3];
        v[0] = Cl2m[0]*f0 + Cl2m[1]*f1 + Cl2m[2]*f2;
        v[1] = Cl2m[3]*f0 + Cl2m[4]*f1 + Cl2m[5]*f2;
        v[2] = Cl2m[6]*f0 + Cl2m[7]*f1 + Cl2m[8]*f2;
#pragma unroll
        for (int m = 0; m < 3; ++m) {
            unsigned short hs = f2bf(v[m]);
            Gh[go + (size_t)m*GLD*GLD] = hs;
            Gl[go + (size_t)m*GLD*GLD] = f2bf(v[m] - bf2f(hs));
        }
    }
}

// ---------------- split-bf16 MFMA GEMM (3-product): out = store_T(A * S) -----------------------
// 64x64 tile, BK=32, global_load_lds staging, double-buffered LDS, coalesced epilogue.
// On the fp32 pass (Cf) with part!=null, also emits per-block partial sums (fused mean).
#define EPLD 68
__global__ __launch_bounds__(256, 3) void gemm_dst(
    const unsigned short* __restrict__ Ah, const unsigned short* __restrict__ Al,
    const unsigned short* __restrict__ Sh, const unsigned short* __restrict__ Sl,
    unsigned short* __restrict__ Ch, unsigned short* __restrict__ Cl,
    float* __restrict__ Cf, const float* __restrict__ helm, float* __restrict__ part)
{
    __shared__ __attribute__((aligned(16))) char ldsraw[32768];
    __shared__ float red[256];
    float* ep = (float*)ldsraw;
    const int id = blockIdx.x;
    const int nblk = id / 96, rr = id - nblk * 96;
    const int b = rr >> 3, mblk = rr & 7;
    const int m0 = mblk << 6, n0 = nblk << 6;
    const int t = threadIdx.x;
    const int wave = t >> 6, lane = t & 63;
    const int wr = wave >> 1, wc = wave & 1;
    const int lr = lane & 15, g = lane >> 4;
    const unsigned short* Abh = Ah + (size_t)b * 262144;
    const unsigned short* Abl = Al + (size_t)b * 262144;

    const int srow = t >> 2;
    const int scol = ((t & 3) ^ ((srow >> 1) & 3)) * 8;
    const size_t gAe = (size_t)(m0 + srow) * 512 + scol;
    const size_t gBe = (size_t)(n0 + srow) * 512 + scol;
    const int ldbase = wave * 1024;

    auto STAGE = [&](int buf, int kt) {
        char* bb = ldsraw + buf * 16384;
        int ke = kt * 32;
        GLDS(Abh + gAe + ke, bb + ldbase);
        GLDS(Abl + gAe + ke, bb + 4096 + ldbase);
        GLDS(Sh  + gBe + ke, bb + 8192 + ldbase);
        GLDS(Sl  + gBe + ke, bb + 12288 + ldbase);
    };

    f32x4 acc[2][2] = {};
    int abyte[2], bbyte[2];
#pragma unroll
    for (int i = 0; i < 2; ++i) {
        int ar = wr*32 + i*16 + lr;
        abyte[i] = ar*64 + ((g ^ ((ar >> 1) & 3)) * 16);
    }
#pragma unroll
    for (int j = 0; j < 2; ++j) {
        int br = wc*32 + j*16 + lr;
        bbyte[j] = 8192 + br*64 + ((g ^ ((br >> 1) & 3)) * 16);
    }

    STAGE(0, 0);
    __syncthreads();
    for (int it = 0; it < 16; ++it) {
        const int buf = it & 1;
        if (it < 15) STAGE(buf ^ 1, it + 1);
        const char* bb = ldsraw + buf * 16384;
        bf16x8 fbh[2], fbl[2];
#pragma unroll
        for (int j = 0; j < 2; ++j) {
            fbh[j] = *(const bf16x8*)(bb + bbyte[j]);
            fbl[j] = *(const bf16x8*)(bb + 4096 + bbyte[j]);
        }
#pragma unroll
        for (int i = 0; i < 2; ++i) {
            bf16x8 fah = *(const bf16x8*)(bb + abyte[i]);
            bf16x8 fal = *(const bf16x8*)(bb + 4096 + abyte[i]);
#pragma unroll
            for (int j = 0; j < 2; ++j) {
                acc[i][j] = __builtin_amdgcn_mfma_f32_16x16x32_bf16(fah, fbh[j], acc[i][j], 0, 0, 0);
                acc[i][j] = __builtin_amdgcn_mfma_f32_16x16x32_bf16(fah, fbl[j], acc[i][j], 0, 0, 0);
                acc[i][j] = __builtin_amdgcn_mfma_f32_16x16x32_bf16(fal, fbh[j], acc[i][j], 0, 0, 0);
            }
        }
        __syncthreads();
    }

    const int mode = b % NL3;
    const float* hp = helm ? (helm + (size_t)mode * NIN * NIN) : nullptr;
#pragma unroll
    for (int i = 0; i < 2; ++i) {
        int mml = wr*32 + i*16 + 4*g;
#pragma unroll
        for (int j = 0; j < 2; ++j) {
            int nnl = wc*32 + j*16 + lr;
            int nn = n0 + nnl;
            float v[4];
#pragma unroll
            for (int r = 0; r < 4; ++r) v[r] = acc[i][j][r];
            if (hp && nn < NIN) {
                int mmb = m0 + mml;
#pragma unroll
                for (int r = 0; r < 4; ++r)
                    if (mmb + r < NIN) v[r] /= hp[(size_t)nn*NIN + mmb + r];
            }
#pragma unroll
            for (int r = 0; r < 4; ++r) ep[nnl*EPLD + mml + r] = v[r];
        }
    }
    __syncthreads();

    float lsum = 0.f;
#pragma unroll
    for (int c = 0; c < 2; ++c) {
        int chunk = t + 256*c;
        int row = chunk >> 3;
        int cb  = (chunk & 7) * 8;
        float v[8];
#pragma unroll
        for (int k = 0; k < 8; ++k) v[k] = ep[row*EPLD + cb + k];
        size_t co = (size_t)b*262144 + (size_t)(n0 + row)*512 + m0 + cb;
        if (Cf) {
#pragma unroll
            for (int k = 0; k < 8; ++k) lsum += v[k];
            f32x4 v0 = {v[0], v[1], v[2], v[3]};
            f32x4 v1 = {v[4], v[5], v[6], v[7]};
            *(f32x4*)(Cf + co)     = v0;
            *(f32x4*)(Cf + co + 4) = v1;
        } else {
            unsigned int h[4], lo[4];
#pragma unroll
            for (int k = 0; k < 4; ++k) {
                unsigned short h0 = f2bf(v[2*k]), h1 = f2bf(v[2*k+1]);
                unsigned short l0 = f2bf(v[2*k]-bf2f(h0)), l1 = f2bf(v[2*k+1]-bf2f(h1));
                h[k]  = (unsigned int)h0 | ((unsigned int)h1 << 16);
                lo[k] = (unsigned int)l0 | ((unsigned int)l1 << 16);
            }
            *(uint4*)(Ch + co) = make_uint4(h[0], h[1], h[2], h[3]);
            *(uint4*)(Cl + co) = make_uint4(lo[0], lo[1], lo[2], lo[3]);
        }
    }

    if (part && mode < 2) {
        red[t] = lsum;
        __syncthreads();
        for (int w = 128; w >= 1; w >>= 1) {
            if (t < w) red[t] += red[t + w];
            __syncthreads();
        }
        if (t == 0) {
            int plane8 = (b / NL3) * 2 + mode;
            part[plane8 * 64 + nblk * 8 + mblk] = red[0];
        }
    }
}

// ---------------- mega: dal + mode->layer + boundary dq + RK4 update (q and p) ------------------
__global__ __launch_bounds__(256) void m2l_mega(
    float* __restrict__ ynext, float* __restrict__ ytmp,
    const float* __restrict__ ycur, const float* __restrict__ kq,
    const float* __restrict__ G, const float* __restrict__ hom,
    const float* __restrict__ Cm2l, const float* __restrict__ Amat,
    const float* __restrict__ alpha, const float* __restrict__ part,
    const float* __restrict__ tarr, int s, float c1, float c2, int accumulate)
{
    __shared__ float sp[128];
    __shared__ float sdal[2];
    const int yy = blockIdx.x * 64 + threadIdx.x;
    const int xx = blockIdx.y * 4 + threadIdx.y;
    const int e  = blockIdx.z;
    const int tt = threadIdx.y * 64 + threadIdx.x;
    const bool act = (xx < NXY && yy < NXY);

    if (tt < 128) sp[tt] = part[(e*2 + (tt >> 6))*64 + (tt & 63)];
    __syncthreads();
    if (tt == 0) {
        float s0 = 0.f, s1 = 0.f;
        for (int j = 0; j < 64; ++j) { s0 += sp[j]; s1 += sp[64 + j]; }
        const float inv = 1.0f / ((float)NXY * (float)NXY);
        float mm0 = s0 * inv, mm1 = s1 * inv;
        sdal[0] = alpha[0]*mm0 + alpha[1]*mm1;
        sdal[1] = alpha[2]*mm0 + alpha[3]*mm1;
    }
    __syncthreads();
    if (!act) return;
    const float dal0 = sdal[0], dal1 = sdal[1];

    auto DP = [&](int px, int py, float* dp) {
        bool inter = (px >= 1 && px <= NIN && py >= 1 && py <= NIN);
        float mv0 = 0.f, mv1 = 0.f, mv2 = 0.f;
        if (inter) {
            size_t gb = (size_t)(e*NL3)*GLD*GLD + (size_t)(px-1)*GLD + (py-1);
            mv0 = G[gb]; mv1 = G[gb + (size_t)GLD*GLD]; mv2 = G[gb + 2*(size_t)GLD*GLD];
        }
        mv0 += dal0 * hom[(size_t)px*NXY + py];
        mv1 += dal1 * hom[(size_t)NXY*NXY + (size_t)px*NXY + py];
        dp[0] = Cm2l[0]*mv0 + Cm2l[1]*mv1 + Cm2l[2]*mv2;
        dp[1] = Cm2l[3]*mv0 + Cm2l[4]*mv1 + Cm2l[5]*mv2;
        dp[2] = Cm2l[6]*mv0 + Cm2l[7]*mv1 + Cm2l[8]*mv2;
    };

    float dp[3];
    DP(xx, yy, dp);

    const bool bnd = (xx == 0 || xx == NXY-1 || yy == 0 || yy == NXY-1);
    float kqv[3];
    if (!bnd) {
#pragma unroll
        for (int l = 0; l < 3; ++l)
            kqv[l] = kq[((size_t)(e*NL3 + l)*NXY + xx)*NXY + yy];
    } else {
        int xn, yn;
        if      (yy == 0)      { xn = xx;    yn = 1; }
        else if (yy == NXY-1)  { xn = xx;    yn = NXY-2; }
        else if (xx == 0)      { xn = 1;     yn = yy; }
        else                   { xn = NXY-2; yn = yy; }
        float dpn[3];
        DP(xn, yn, dpn);
#pragma unroll
        for (int l = 0; l < 3; ++l) {
            float lpb = ZFBCf * INVF0DX2f * (dpn[l] - dp[l]);
            kqv[l] = lpb - (Amat[l*3+0]*dp[0] + Amat[l*3+1]*dp[1] + Amat[l*3+2]*dp[2]);
        }
    }

    const float dt = tarr[s+1] - tarr[s];
    const float a1 = c1 * dt, a2 = c2 * dt;
#pragma unroll
    for (int l = 0; l < 3; ++l) {
        size_t oq = ((size_t)(e*NL3 + l)*NXY + xx)*NXY + yy;
        size_t op = oq + FS;
        float xq = ycur[oq], xp = ycur[op];
        float bq = accumulate ? ynext[oq] : xq;
        float bp = accumulate ? ynext[op] : xp;
        ynext[oq] = bq + a1 * kqv[l];
        ynext[op] = bp + a1 * dp[l];
        if (ytmp) {
            ytmp[oq] = xq + a2 * kqv[l];
            ytmp[op] = xp + a2 * dp[l];
        }
    }
}

__global__ void copy_kernel(float4* __restrict__ out, const float4* __restrict__ in, long n4) {
    for (long i = (long)blockIdx.x * blockDim.x + threadIdx.x; i < n4;
         i += (long)gridDim.x * blockDim.x)
        out[i] = in[i];
}

// ===============================================================================================
extern "C" void kernel_launch(void* const* d_in, const int* in_sizes, int n_in,
                              void* d_out, int out_size, void* d_ws, size_t ws_size,
                              hipStream_t stream) {
    const float* y0    = (const float*)d_in[0];
    const float* tarr  = (const float*)d_in[1];
    const float* Amat  = (const float*)d_in[2];
    const float* Cl2m  = (const float*)d_in[3];
    const float* Cm2l  = (const float*)d_in[4];
    const float* helm  = (const float*)d_in[5];
    const float* alpha = (const float*)d_in[6];
    const float* hom   = (const float*)d_in[7];
    const float* wind  = (const float*)d_in[8];
    float* out = (float*)d_out;
    char* base = (char*)d_ws;

    unsigned short* Sh = (unsigned short*)base;                       // 512 KB
    unsigned short* Sl = (unsigned short*)(base + 512*1024);          // 512 KB
    float* ytmp = (float*)(base + 1024*1024);                         // 2*FS floats
    float* kq   = ytmp + 2*FS;                                        // FS floats
    char*  REGb = (char*)(kq + FS);
    unsigned short* P0h = (unsigned short*)REGb;
    unsigned short* P0l = P0h + GSZ;
    unsigned short* P1h = P0l + GSZ;
    unsigned short* P1l = P1h + GSZ;
    float* R4 = (float*)REGb;                                         // aliases P0h/P0l (safe)
    float* partial = (float*)(REGb + (size_t)2*FS*sizeof(float));

    const dim3 bSt(64, 4, 1);
    const dim3 gM(9, 129, NE4);
    const dim3 gF(8, 32, NE4);
    const dim3 gG(768, 1, 1);
    const long n4 = 2*FS/4;

    initS_kernel<<<dim3(2, GLD), 256, 0, stream>>>(Sh, Sl);
    copy_kernel<<<1024, 256, 0, stream>>>((float4*)out, (const float4*)y0, n4);

    auto evalstep = [&](const float* y, const float* ycur, float* ynext, float* otmp,
                        int s, float c1, float c2, int accumulate) {
        fused_rhs_l2m<<<gF, 256, 0, stream>>>(kq, P0h, P0l, y, wind, Cl2m);
        gemm_dst<<<gG, 256, 0, stream>>>(P0h, P0l, Sh, Sl, P1h, P1l, nullptr, nullptr, nullptr);
        gemm_dst<<<gG, 256, 0, stream>>>(P1h, P1l, Sh, Sl, P0h, P0l, nullptr, helm, nullptr);
        gemm_dst<<<gG, 256, 0, stream>>>(P0h, P0l, Sh, Sl, P1h, P1l, nullptr, nullptr, nullptr);
        gemm_dst<<<gG, 256, 0, stream>>>(P1h, P1l, Sh, Sl, nullptr, nullptr, R4, nullptr, partial);
        m2l_mega<<<gM, bSt, 0, stream>>>(ynext, otmp, ycur, kq, R4, hom, Cm2l, Amat,
                                         alpha, partial, tarr, s, c1, c2, accumulate);
    };

    for (int s = 0; s < NSTEPS; ++s) {
        float* ycur  = out + (size_t)s * 2 * FS;
        float* ynext = out + (size_t)(s + 1) * 2 * FS;
        evalstep(ycur, ycur, ynext, ytmp, s, 1.f/6.f, 0.5f, 0);
        evalstep(ytmp, ycur, ynext, ytmp, s, 2.f/6.f, 0.5f, 1);
        evalstep(ytmp, ycur, ynext, ytmp, s, 2.f/6.f, 1.0f, 1);
        evalstep(ytmp, ycur, ynext, nullptr, s, 1.f/6.f, 0.f, 1);
    }
}